// Round 4
// baseline (43.664 us; speedup 1.0000x reference)
//
#include <hip/hip_runtime.h>
#include <math.h>

// Problem constants: B=32, H=100, C=50, D=400, HID=400
#define B_   32
#define H_   100
#define C_   50
#define D_   400
#define HID_ 400
#define NTILES 7                    // ceil(D/64)
#define NBLOCKS (B_ * NTILES)       // 224 <= 256 CUs -> all co-resident
#define NTHREADS 256
#define NWAVES 4
#define TOTWAVES (NBLOCKS * NWAVES) // 896

#define NEGF (-3.4028234663852886e38f)  // finfo(float32).min

// Algebraic collapse (verified R1-R3, absmax 1.5e-5):
//   weights[b,h] = softmax_h(mask ? hist[b,h]·u : finfo.min), u = W1[D:,:]@w2
//   out[b,c,:]   = mask_cand[b,c] ? sum_h w[b,h]*hist[b,h,:] : 0
//
// R2 (3 kernels) = 17 us, dominated by 3x dispatch. R3 fusion regressed (27us)
// because it SERIALIZED the score phase. This round: single kernel, R2's
// parallel decomposition for every phase, lock-free grid syncs between phases.
// 224 blocks are guaranteed co-resident (<= 256 CUs, tiny resources), so
// spin-wait on a device-scope atomic counter cannot deadlock.

__device__ __forceinline__ float wave_reduce_add(float v) {
    #pragma unroll
    for (int off = 32; off; off >>= 1) v += __shfl_xor(v, off, 64);
    return v;
}

__device__ __forceinline__ void grid_sync(unsigned* flag) {
    __syncthreads();                 // all block's prior stores done (block scope)
    if (threadIdx.x == 0) {
        // release our stores device-wide, count in
        __hip_atomic_fetch_add(flag, 1u, __ATOMIC_ACQ_REL, __HIP_MEMORY_SCOPE_AGENT);
        // spin until all blocks arrived (acquire pairs with their releases)
        while (__hip_atomic_load(flag, __ATOMIC_ACQUIRE, __HIP_MEMORY_SCOPE_AGENT) < NBLOCKS)
            __builtin_amdgcn_s_sleep(8);
    }
    __syncthreads();                 // rest of block waits on thread 0
}

__global__ __launch_bounds__(NTHREADS)
void fused_all(const float* __restrict__ hist,      // (B,H,D)
               const int*   __restrict__ mask_hist, // (B,H)
               const int*   __restrict__ mask_cand, // (B,C)
               const float* __restrict__ W1,        // (2D,HID)
               const float* __restrict__ w2,        // (HID)
               unsigned*    __restrict__ flags,     // 2 counters, zeroed per call
               float*       __restrict__ u,         // (D) scratch
               float*       __restrict__ s,         // (B*H) scratch
               float*       __restrict__ out)       // (B,C,D)
{
    __shared__ float w_lds[H_];
    __shared__ float part[NWAVES][64];

    const int lane = threadIdx.x & 63;
    const int wave = threadIdx.x >> 6;
    const int wg   = blockIdx.x * NWAVES + wave;    // global wave id, 0..895

    // ---- Phase A: u[row] = dot(W1[D+row,:], w2), one row per wave ----
    if (wg < D_) {
        const float4* r4 = (const float4*)(W1 + (size_t)(D_ + wg) * HID_);
        const float4* w4 = (const float4*)w2;
        float4 a0 = r4[lane], b0 = w4[lane];
        float acc = a0.x*b0.x + a0.y*b0.y + a0.z*b0.z + a0.w*b0.w;
        if (lane < 36) {                            // 100 float4/row = 64 + 36
            float4 a1 = r4[64 + lane], b1 = w4[64 + lane];
            acc += a1.x*b1.x + a1.y*b1.y + a1.z*b1.z + a1.w*b1.w;
        }
        acc = wave_reduce_add(acc);
        if (lane == 0) u[wg] = acc;
    }
    grid_sync(&flags[0]);

    // ---- Phase B: s[row] = mask ? hist_row · u : NEG, rows strided by 896 ----
    const float4* u4 = (const float4*)u;
    const float4  ua = u4[lane];
    const float4  ub = (lane < 36) ? u4[64 + lane] : make_float4(0.f,0.f,0.f,0.f);
    for (int row = wg; row < B_ * H_; row += TOTWAVES) {   // <=4 rows per wave
        const float4* r4 = (const float4*)(hist + (size_t)row * D_);
        float4 a = r4[lane];
        float acc = a.x*ua.x + a.y*ua.y + a.z*ua.z + a.w*ua.w;
        if (lane < 36) {
            float4 a1 = r4[64 + lane];
            acc += a1.x*ub.x + a1.y*ub.y + a1.z*ub.z + a1.w*ub.w;
        }
        acc = wave_reduce_add(acc);
        if (lane == 0) s[row] = mask_hist[row] ? acc : NEGF;
    }
    grid_sync(&flags[1]);

    // ---- Phase C: per (b, d-tile): softmax + weighted sum + masked stores ----
    // XCD-residue decode: 7 tiles of a b share blockIdx%8 (L2 locality hint).
    const int x    = blockIdx.x & 7;
    const int k    = blockIdx.x >> 3;               // 0..27
    const int q    = k / 7;                         // 0..3
    const int b    = x + 8 * q;                     // 0..31
    const int tile = k - 7 * q;                     // 0..6
    const int d0   = tile * 64;
    const int d    = d0 + lane;                     // may exceed 399 on tile 6

    // softmax over s[b,0..99], redundant per wave
    const float* sb = s + b * H_;
    const float s0 = sb[lane];
    const float s1 = (lane < 36) ? sb[64 + lane] : -INFINITY;
    float m = fmaxf(s0, s1);
    #pragma unroll
    for (int off = 32; off; off >>= 1) m = fmaxf(m, __shfl_xor(m, off, 64));
    const float e0 = expf(s0 - m);
    const float e1 = (lane < 36) ? expf(s1 - m) : 0.f;
    const float inv = 1.f / wave_reduce_add(e0 + e1);
    if (wave == 0) {
        w_lds[lane] = e0 * inv;
        if (lane < 36) w_lds[64 + lane] = e1 * inv;
    }
    __syncthreads();

    // uv[d] partials: wave w owns h in [25w, 25w+25)
    const float* hb = hist + (size_t)b * H_ * D_;
    float acc = 0.f;
    if (d < D_) {
        const int h0 = wave * 25;
        #pragma unroll
        for (int i = 0; i < 25; i++)
            acc = fmaf(w_lds[h0 + i], hb[(size_t)(h0 + i) * D_ + d], acc);
    }
    part[wave][lane] = acc;
    __syncthreads();

    const float uv = part[0][lane] + part[1][lane] + part[2][lane] + part[3][lane];
    const int* mc  = mask_cand + b * C_;
    float* outb = out + (size_t)b * C_ * D_ + d0;
    if (d < D_) {
        for (int c = wave; c < C_; c += 4)
            outb[(size_t)c * D_ + lane] = mc[c] ? uv : 0.f;
    }
}

extern "C" void kernel_launch(void* const* d_in, const int* in_sizes, int n_in,
                              void* d_out, int out_size, void* d_ws, size_t ws_size,
                              hipStream_t stream) {
    // inputs: 0 hist(B,H,D) f32, 1 cand [unused], 2 mask_hist(B,H) i32,
    //         3 mask_cand(B,C) i32, 4 W1(2D,HID) f32, 5 b1 [unused],
    //         6 w2(HID) f32, 7 b2 [unused]
    const float* hist      = (const float*)d_in[0];
    const int*   mask_hist = (const int*)d_in[2];
    const int*   mask_cand = (const int*)d_in[3];
    const float* W1        = (const float*)d_in[4];
    const float* w2        = (const float*)d_in[6];
    float* out = (float*)d_out;

    unsigned* flags = (unsigned*)d_ws;                       // 2 counters
    float*    u     = (float*)((char*)d_ws + 512);           // 400 floats
    float*    s     = (float*)((char*)d_ws + 4096);          // 3200 floats

    // zero the sync counters every call (graph-capturable async memset)
    hipMemsetAsync(d_ws, 0, 256, stream);
    fused_all<<<NBLOCKS, NTHREADS, 0, stream>>>(hist, mask_hist, mask_cand,
                                                W1, w2, flags, u, s, out);
}

// Round 5
// 16.631 us; speedup vs baseline: 2.6254x; 2.6254x over previous
//
#include <hip/hip_runtime.h>
#include <math.h>

// Problem constants: B=32, H=100, C=50, D=400, HID=400
#define B_   32
#define H_   100
#define C_   50
#define D_   400
#define HID_ 400
#define ROWS (B_ * H_)              // 3200 score rows
#define T_   7                      // d-tiles of 64 floats (tile 6 = 16 floats)
#define RCH  32                     // row-chunks of 100 rows each

#define NEGF (-3.4028234663852886e38f)  // finfo(float32).min

// Algebraic collapse (verified R1-R4, absmax 1.5e-5):
//   weights[b,h] = softmax_h(mask ? hist[b,h]·u : finfo.min), u = W1[D:,:]@w2
//   out[b,c,:]   = mask_cand[b,c] ? sum_h w[b,h]*hist[b,h,:] : 0
//
// History: R2 = 3 small kernels, 17us (dispatch-bound). R3 fused but
// serialized (27us). R4 atomic grid-sync = 43us (cross-XCD coherence is
// brutal). This round: 2 dispatches by breaking the u->s dependency with
// d-axis partial scores. Block (t,r) recomputes the 64-wide u-slice of its
// tile (cheap, W1h slice is L2-hot across the 32 r-blocks) and writes
// s_part[t][rows]. K_out sums the 7 partials in fixed order (deterministic,
// no atomics), then softmax + weighted sum + masked broadcast store.

__device__ __forceinline__ float wave_reduce_add(float v) {
    #pragma unroll
    for (int off = 32; off; off >>= 1) v += __shfl_xor(v, off, 64);
    return v;
}

// ---- K_scores: grid = T_*RCH = 224 blocks, 512 threads ----
__global__ __launch_bounds__(512)
void k_scores(const float* __restrict__ hist,   // (3200, 400)
              const float* __restrict__ W1,     // (800, 400)
              const float* __restrict__ w2,     // (400)
              float* __restrict__ s_part) {     // (7, 3200)
    __shared__ float4 u4_lds[16];               // u-slice of this tile (64 f)

    const int t    = blockIdx.x >> 5;           // 0..6
    const int r    = blockIdx.x & 31;           // 0..31
    const int d0   = t * 64;
    const int dt   = (d0 + 64 <= D_) ? 64 : (D_ - d0);   // 64, last tile 16
    const int lane = threadIdx.x & 63;
    const int wave = threadIdx.x >> 6;

    // --- Phase 1: u[d0+i] = dot(W1[D+d0+i,:], w2), i striped over 8 waves ---
    const float4* w24 = (const float4*)w2;      // 100 float4
    for (int i = wave; i < dt; i += 8) {
        const float4* row4 = (const float4*)(W1 + (size_t)(D_ + d0 + i) * HID_);
        float4 a0 = row4[lane], b0 = w24[lane];
        float acc = a0.x*b0.x + a0.y*b0.y + a0.z*b0.z + a0.w*b0.w;
        if (lane < 36) {                         // 100 f4 per row = 64 + 36
            float4 a1 = row4[64 + lane], b1 = w24[64 + lane];
            acc += a1.x*b1.x + a1.y*b1.y + a1.z*b1.z + a1.w*b1.w;
        }
        acc = wave_reduce_add(acc);
        if (lane == 0) ((float*)u4_lds)[i] = acc;
    }
    __syncthreads();

    // --- Phase 2: s_part[t][row] = hist[row, d0:d0+dt] . u_slice ---
    // 64 lanes = 4 rows x 16 lanes; each 16-lane group does one row (16 f4).
    const int l16 = lane & 15;
    const int sub = lane >> 4;
    const int dt4 = dt >> 2;                    // 16 or 4
    const float4 uu = (l16 < dt4) ? u4_lds[l16] : make_float4(0.f,0.f,0.f,0.f);
    const float4* h4 = (const float4*)hist;     // row stride 100 f4
    float* sp = s_part + (size_t)t * ROWS;
    const int row0 = r * 100;
    #pragma unroll
    for (int p = 0; p < 4; p++) {
        const int rl = p * 32 + wave * 4 + sub; // 0..127, unique
        if (rl < 100) {
            const int row = row0 + rl;
            float4 a = (l16 < dt4) ? h4[(size_t)row * 100 + t * 16 + l16]
                                   : make_float4(0.f,0.f,0.f,0.f);
            float acc = a.x*uu.x + a.y*uu.y + a.z*uu.z + a.w*uu.w;
            #pragma unroll
            for (int off = 8; off; off >>= 1)   // reduce within 16-lane group
                acc += __shfl_xor(acc, off, 64);
            if (l16 == 0) sp[row] = acc;
        }
    }
}

// ---- K_out: grid = 32*7 = 224 blocks (b,tile), 256 threads ----
__global__ __launch_bounds__(256)
void k_out(const float* __restrict__ hist, const float* __restrict__ s_part,
           const int* __restrict__ mask_hist, const int* __restrict__ mask_cand,
           float* __restrict__ out) {
    __shared__ float s_lds[H_];
    __shared__ float w_lds[H_];
    __shared__ float part[4][64];

    const int b    = blockIdx.x / T_;
    const int tile = blockIdx.x % T_;
    const int d0   = tile * 64;
    const int lane = threadIdx.x & 63;
    const int wave = threadIdx.x >> 6;
    const int tid  = threadIdx.x;

    // --- reduce partials (fixed order -> deterministic) + mask ---
    if (tid < H_) {
        const int row = b * H_ + tid;
        float sum = 0.f;
        #pragma unroll
        for (int t = 0; t < T_; t++) sum += s_part[(size_t)t * ROWS + row];
        s_lds[tid] = mask_hist[row] ? sum : NEGF;
    }
    __syncthreads();

    // --- softmax over s_lds[0..99], redundant per wave ---
    const float s0 = s_lds[lane];
    const float s1 = (lane < 36) ? s_lds[64 + lane] : -INFINITY;
    float m = fmaxf(s0, s1);
    #pragma unroll
    for (int off = 32; off; off >>= 1) m = fmaxf(m, __shfl_xor(m, off, 64));
    const float e0 = expf(s0 - m);
    const float e1 = (lane < 36) ? expf(s1 - m) : 0.f;
    const float inv = 1.f / wave_reduce_add(e0 + e1);
    if (wave == 0) {
        w_lds[lane] = e0 * inv;
        if (lane < 36) w_lds[64 + lane] = e1 * inv;
    }
    __syncthreads();

    // --- uv[d0+lane] partials: wave w owns h in [25w, 25w+25) ---
    const float* hb = hist + (size_t)b * H_ * D_;
    const int d = d0 + lane;                    // may exceed 399 on tile 6
    float acc = 0.f;
    if (d < D_) {
        const int h0 = wave * 25;
        #pragma unroll
        for (int i = 0; i < 25; i++)
            acc = fmaf(w_lds[h0 + i], hb[(size_t)(h0 + i) * D_ + d], acc);
    }
    part[wave][lane] = acc;
    __syncthreads();

    // --- masked broadcast store of 50 c's ---
    const float uv = part[0][lane] + part[1][lane] + part[2][lane] + part[3][lane];
    const int* mc  = mask_cand + b * C_;
    float* outb = out + (size_t)b * C_ * D_ + d0;
    if (d < D_) {
        for (int c = wave; c < C_; c += 4)
            outb[(size_t)c * D_ + lane] = mc[c] ? uv : 0.f;
    }
}

extern "C" void kernel_launch(void* const* d_in, const int* in_sizes, int n_in,
                              void* d_out, int out_size, void* d_ws, size_t ws_size,
                              hipStream_t stream) {
    // inputs: 0 hist(B,H,D) f32, 1 cand [unused], 2 mask_hist(B,H) i32,
    //         3 mask_cand(B,C) i32, 4 W1(2D,HID) f32, 5 b1 [unused],
    //         6 w2(HID) f32, 7 b2 [unused]
    const float* hist      = (const float*)d_in[0];
    const int*   mask_hist = (const int*)d_in[2];
    const int*   mask_cand = (const int*)d_in[3];
    const float* W1        = (const float*)d_in[4];
    const float* w2        = (const float*)d_in[6];
    float* out = (float*)d_out;

    float* s_part = (float*)d_ws;   // 7*3200 floats = 89.6 KB scratch

    k_scores<<<T_ * RCH, 512, 0, stream>>>(hist, W1, w2, s_part);
    k_out   <<<B_ * T_,  256, 0, stream>>>(hist, s_part, mask_hist, mask_cand, out);
}

// Round 6
// 14.679 us; speedup vs baseline: 2.9747x; 1.1330x over previous
//
#include <hip/hip_runtime.h>
#include <math.h>

// Problem constants: B=32, H=100, C=50, D=400, HID=400
#define B_   32
#define H_   100
#define C_   50
#define D_   400
#define HID_ 400
#define ROWS (B_ * H_)              // 3200 score rows
#define T_   7                      // d-tiles of 64 floats (tile 6 = 16 floats)
#define SPLD 8                      // s_part row stride (7 partials + pad)

#define NEGF (-3.4028234663852886e38f)  // finfo(float32).min

// Algebraic collapse (verified R1-R5, absmax 1.5e-5):
//   weights[b,h] = softmax_h(mask ? hist[b,h]·u : finfo.min), u = W1[D:,:]@w2
//   out[b,c,:]   = mask_cand[b,c] ? sum_h w[b,h]*hist[b,h,:] : 0
//
// R4/R5 established: in-graph dispatch overhead ~0.3us; the ~16us is kernel
// execution dominated by serial load-latency chains. This round keeps the
// 2-kernel structure and attacks the chains:
//  - k_scores: u-slice rows via 16-lane groups (2 indep rounds, not 8 serial);
//    hist loads hoisted to kernel top (they don't depend on u) so HBM latency
//    hides under the u-slice phase.
//  - k_out: all 25 hist loads prefetched to registers before the s_part
//    reduce + softmax (they don't depend on weights); s_part relaid [row][8]
//    so the 7 partials are 2 contiguous float4 loads.

__device__ __forceinline__ float dot4(float4 a, float4 b) {
    return fmaf(a.x, b.x, fmaf(a.y, b.y, fmaf(a.z, b.z, a.w * b.w)));
}

// ---- K_scores: grid = 7*32 = 224 blocks, 512 threads ----
// Block (t, r): computes u-slice for d in [64t, 64t+dt), then partial scores
// s_part[row][t] = hist[row, 64t:64t+dt] . u_slice for rows [100r, 100r+100).
__global__ __launch_bounds__(512)
void k_scores(const float* __restrict__ hist,   // (3200, 400)
              const float* __restrict__ W1,     // (800, 400)
              const float* __restrict__ w2,     // (400)
              float* __restrict__ s_part) {     // (3200, 8)
    __shared__ float u_lds[64];

    const int t    = blockIdx.x >> 5;           // 0..6
    const int r    = blockIdx.x & 31;           // 0..31
    const int d0   = t * 64;
    const int dt   = (t < 6) ? 64 : 16;
    const int dt4  = dt >> 2;                   // 16 or 4
    const int tid  = threadIdx.x;
    const int lane = tid & 63;
    const int wave = tid >> 6;
    const int l16  = lane & 15;
    const int sub  = lane >> 4;                 // 0..3
    const int g    = tid >> 4;                  // 16-lane group id, 0..31

    // ---- Hoisted hist loads (independent of u): 4 rows per lane-group ----
    const float4* h4 = (const float4*)hist;     // row stride 100 float4
    const bool cload = (l16 < dt4);
    float4 ha[4];
    int   rown[4];
    #pragma unroll
    for (int p = 0; p < 4; p++) {
        const int rl = p * 32 + wave * 4 + sub; // 0..127
        rown[p] = r * 100 + rl;
        ha[p] = (rl < 100 && cload)
              ? h4[(size_t)rown[p] * 100 + t * 16 + l16]
              : make_float4(0.f, 0.f, 0.f, 0.f);
    }

    // ---- Phase 1: u[i] = dot(W1[D+d0+i,:], w2), one row per 16-lane group ----
    const float4* w24 = (const float4*)w2;      // 100 float4
    #pragma unroll 2
    for (int i = g; i < dt; i += 32) {
        const float4* row4 = (const float4*)(W1 + (size_t)(D_ + d0 + i) * HID_);
        float acc = 0.f;
        #pragma unroll
        for (int k = 0; k < 6; k++)             // l16 + 16k <= 95 < 100 always
            acc += dot4(row4[l16 + 16 * k], w24[l16 + 16 * k]);
        if (l16 < 4)                            // tail: 96..99
            acc += dot4(row4[96 + l16], w24[96 + l16]);
        #pragma unroll
        for (int off = 8; off; off >>= 1)
            acc += __shfl_xor(acc, off, 64);
        if (l16 == 0) u_lds[i] = acc;
    }
    __syncthreads();

    // ---- Phase 2: partial scores with the prefetched hist values ----
    const float4 uu = cload ? ((const float4*)u_lds)[l16]
                            : make_float4(0.f, 0.f, 0.f, 0.f);
    #pragma unroll
    for (int p = 0; p < 4; p++) {
        const int rl = p * 32 + wave * 4 + sub;
        float acc = dot4(ha[p], uu);
        #pragma unroll
        for (int off = 8; off; off >>= 1)       // reduce within 16-lane group
            acc += __shfl_xor(acc, off, 64);
        if (rl < 100 && l16 == 0)
            s_part[(size_t)rown[p] * SPLD + t] = acc;
    }
}

// ---- K_out: grid = 32*7 = 224 blocks (b,tile), 256 threads ----
__global__ __launch_bounds__(256)
void k_out(const float* __restrict__ hist, const float* __restrict__ s_part,
           const int* __restrict__ mask_hist, const int* __restrict__ mask_cand,
           float* __restrict__ out) {
    __shared__ float s_lds[H_];
    __shared__ float part[4][64];

    const int b    = blockIdx.x / T_;
    const int tile = blockIdx.x % T_;
    const int d0   = tile * 64;
    const int lane = threadIdx.x & 63;
    const int wave = threadIdx.x >> 6;
    const int tid  = threadIdx.x;
    const int d    = d0 + lane;                 // may exceed 399 on tile 6
    const bool dv  = (d < D_);

    // ---- Prefetch: 25 hist values per thread (independent of softmax) ----
    const float* hb = hist + (size_t)b * H_ * D_;
    const int h0 = wave * 25;
    float r[25];
    #pragma unroll
    for (int i = 0; i < 25; i++)
        r[i] = dv ? hb[(size_t)(h0 + i) * D_ + d] : 0.f;

    // ---- s_part reduce (fixed order, deterministic) + mask ----
    if (tid < H_) {
        const int row = b * H_ + tid;
        const float4* sp4 = (const float4*)(s_part + (size_t)row * SPLD);
        float4 a = sp4[0], c = sp4[1];          // 7 partials + pad
        float sum = ((a.x + a.y) + (a.z + a.w)) + ((c.x + c.y) + c.z);
        s_lds[tid] = mask_hist[row] ? sum : NEGF;
    }
    __syncthreads();

    // ---- softmax over s_lds[0..99], redundant per wave ----
    const float s0 = s_lds[lane];
    const float s1 = (lane < 36) ? s_lds[64 + lane] : -INFINITY;
    float m = fmaxf(s0, s1);
    #pragma unroll
    for (int off = 32; off; off >>= 1) m = fmaxf(m, __shfl_xor(m, off, 64));
    const float e0 = expf(s0 - m);
    const float e1 = (lane < 36) ? expf(s1 - m) : 0.f;
    float ps = e0 + e1;
    #pragma unroll
    for (int off = 32; off; off >>= 1) ps += __shfl_xor(ps, off, 64);
    const float inv = 1.f / ps;
    // each wave writes its own h-range of weights: h = wave*25 + i needs
    // w[h] for h in [0,100); store all (wave 0's view) — but every wave has
    // identical e/inv values, so let wave 0 publish and all read after sync.
    if (wave == 0) {
        s_lds[lane] = e0 * inv;                 // reuse s_lds as weights
        if (lane < 36) s_lds[64 + lane] = e1 * inv;
    }
    __syncthreads();

    // ---- weighted sum with prefetched values ----
    float acc0 = 0.f, acc1 = 0.f;
    #pragma unroll
    for (int i = 0; i < 24; i += 2) {
        acc0 = fmaf(s_lds[h0 + i],     r[i],     acc0);
        acc1 = fmaf(s_lds[h0 + i + 1], r[i + 1], acc1);
    }
    acc0 = fmaf(s_lds[h0 + 24], r[24], acc0);
    part[wave][lane] = acc0 + acc1;
    __syncthreads();

    // ---- masked broadcast store of 50 c's ----
    const float uv = part[0][lane] + part[1][lane] + part[2][lane] + part[3][lane];
    const int* mc  = mask_cand + b * C_;
    float* outb = out + (size_t)b * C_ * D_ + d0;
    if (dv) {
        for (int c = wave; c < C_; c += 4)
            outb[(size_t)c * D_ + lane] = mc[c] ? uv : 0.f;
    }
}

extern "C" void kernel_launch(void* const* d_in, const int* in_sizes, int n_in,
                              void* d_out, int out_size, void* d_ws, size_t ws_size,
                              hipStream_t stream) {
    // inputs: 0 hist(B,H,D) f32, 1 cand [unused], 2 mask_hist(B,H) i32,
    //         3 mask_cand(B,C) i32, 4 W1(2D,HID) f32, 5 b1 [unused],
    //         6 w2(HID) f32, 7 b2 [unused]
    const float* hist      = (const float*)d_in[0];
    const int*   mask_hist = (const int*)d_in[2];
    const int*   mask_cand = (const int*)d_in[3];
    const float* W1        = (const float*)d_in[4];
    const float* w2        = (const float*)d_in[6];
    float* out = (float*)d_out;

    float* s_part = (float*)d_ws;   // 3200*8 floats = 102.4 KB scratch

    k_scores<<<T_ * 32, 512, 0, stream>>>(hist, W1, w2, s_part);
    k_out   <<<B_ * T_, 256, 0, stream>>>(hist, s_part, mask_hist, mask_cand, out);
}